// Round 8
// baseline (84.179 us; speedup 1.0000x reference)
//
#include <hip/hip_runtime.h>

#define NN 50000
#define DD 50
#define RR 64
#define SUBS 32                      // sub-bins per relation
#define BINS (RR * SUBS)             // 2048
#define CAP 128                      // fixed slots per bin (mean ~49; 11.5-sigma margin)
#define GPB (CAP / 16)               // 8 groups max per bin
#define SLOTS (BINS * CAP)           // 262144
#define WLMAX 8192                   // >= sum ceil(cnt/16) <= (E + BINS*15)/16 = 8170

// meta (ints): [0,BINS) cursors | [WL_OFF,+WLMAX) worklist | [SD_OFF,+2*SLOTS) int2 slots
#define WL_OFF 2048
#define SD_OFF (WL_OFF + WLMAX)          // 10240
#define META_INTS (SD_OFF + 2 * SLOTS)   // 534528 ints = 2.09 MB
#define WB_BYTE (META_INTS * 4)          // then wb: RR*64*64*2 = 512 KB

typedef __attribute__((ext_vector_type(8))) short bf16x8;
typedef __attribute__((ext_vector_type(4))) float f32x4;

__device__ __forceinline__ unsigned short f2b(float f) {   // f32 -> bf16 RNE
    unsigned u = __float_as_uint(f);
    u = (u + 0x7fffu + ((u >> 16) & 1u)) >> 16;
    return (unsigned short)u;
}

// Zero out[], init cursors + worklist, build W^T bf16: wb[r][n][k] = W[r][k][n],
// zero-padded to 64x64. Reads of w are coalesced (n fastest); scattered 2B
// writes into the 512 KB wb are L2-absorbed.
__global__ void init_kernel(float4* __restrict__ out4, int n4, int* __restrict__ meta,
                            unsigned short* __restrict__ wb, const float* __restrict__ w) {
    int i = blockIdx.x * blockDim.x + threadIdx.x;
    int stride = gridDim.x * blockDim.x;
    for (int j = i; j < n4; j += stride) out4[j] = make_float4(0.f, 0.f, 0.f, 0.f);
    if (i < BINS) meta[i] = i * CAP;
    if (i < WLMAX) meta[WL_OFF + i] = -1;
    for (int j = i; j < RR * 64 * 64; j += stride) {
        int r = j >> 12, d = (j >> 6) & 63, n = j & 63;
        float v = (n < DD && d < DD) ? w[r * (DD * DD) + d * DD + n] : 0.f;
        wb[(r << 12) + (n << 6) + d] = f2b(v);
    }
}

// Atomic-append each edge into its (rel, e&31) bin's fixed region.
__global__ void scatter_kernel(const int* __restrict__ src, const int* __restrict__ dst,
                               const int* __restrict__ rel, int E, int* __restrict__ meta) {
    int e = blockIdx.x * blockDim.x + threadIdx.x;
    if (e >= E) return;
    int sb = (rel[e] << 5) | (e & 31);
    int p = atomicAdd(&meta[sb], 1);
    if (p < (sb + 1) * CAP)                      // overflow guard (never fires at 11.5 sigma)
        ((int2*)(meta + SD_OFF))[p] = make_int2(src[e], dst[e]);
}

// One block: turn bin counts into a dense packed worklist: entry = (g<<5)|nv.
__global__ __launch_bounds__(1024) void compact_kernel(int* __restrict__ meta) {
    __shared__ int part[1024];
    int tid = threadIdx.x;
    int b0 = tid * 2, b1 = tid * 2 + 1;
    int c0 = meta[b0] - b0 * CAP; c0 = c0 < 0 ? 0 : (c0 > CAP ? CAP : c0);
    int c1 = meta[b1] - b1 * CAP; c1 = c1 < 0 ? 0 : (c1 > CAP ? CAP : c1);
    int ng0 = (c0 + 15) >> 4, ng1 = (c1 + 15) >> 4;
    part[tid] = ng0 + ng1;
    __syncthreads();
    if (tid == 0) {
        int cum = 0;
        for (int t = 0; t < 1024; ++t) { int v = part[t]; part[t] = cum; cum += v; }
    }
    __syncthreads();
    int off = part[tid];
    for (int gi = 0; gi < ng0; ++gi) {
        int nv = c0 - gi * 16; nv = nv > 16 ? 16 : nv;
        meta[WL_OFF + off + gi] = ((b0 * GPB + gi) << 5) | nv;
    }
    off += ng0;
    for (int gi = 0; gi < ng1; ++gi) {
        int nv = c1 - gi * 16; nv = nv > 16 ? 16 : nv;
        meta[WL_OFF + off + gi] = ((b1 * GPB + gi) << 5) | nv;
    }
}

// One wave = one dense worklist entry = 16 edges of one relation.
// A = h rows [16x50] bf16 (in-register convert), B = W^T frags (L2-resident),
// 8x mfma_f32_16x16x32_bf16, coalesced row-atomic scatter.
__global__ __launch_bounds__(256) void edge_kernel(const float* __restrict__ h,
                                                   const unsigned short* __restrict__ wb,
                                                   const int* __restrict__ meta,
                                                   float* __restrict__ out) {
    int lane = threadIdx.x & 63;
    int widx = __builtin_amdgcn_readfirstlane((blockIdx.x << 2) + (threadIdx.x >> 6));
    int entry = meta[WL_OFF + widx];             // wave-uniform -> s_load
    if (entry < 0) return;
    entry = __builtin_amdgcn_readfirstlane(entry);
    int nv = entry & 31;
    int g  = entry >> 5;
    int sb = g >> 3;                              // GPB = 8
    int gi = g & (GPB - 1);
    int r  = sb >> 5;                             // SUBS = 32
    int base = sb * CAP + gi * 16;

    // lanes 0..15 hold the group's edges; broadcast via shfl
    int sv0 = 0, dv0 = -1;
    if (lane < nv) {
        int2 sd = ((const int2*)(meta + SD_OFF))[base + lane];
        sv0 = sd.x; dv0 = sd.y;
    }
    int sv = __shfl(sv0, lane & 15);              // src of my A row (row = lane&15)
    int ch = lane >> 4;                           // k-chunk 0..3

    const float* __restrict__ hrow = h + (size_t)sv * DD;

    // A K-step 0: elements k = ch*8 .. +7 (< 32 < 50): always in-bounds.
    const float2* hp0 = (const float2*)(hrow + ch * 8);
    float2 q0 = hp0[0], q1 = hp0[1], q2 = hp0[2], q3 = hp0[3];

    // A K-step 1: k = 32+ch*8 .. +7; only pairs fully inside the 50-elem row
    // load; the rest are zero (pair with zero-padded B columns k>=50).
    int kb = 32 + ch * 8;
    const float2 z2 = make_float2(0.f, 0.f);
    float2 q4 = (kb + 1 < DD) ? *(const float2*)(hrow + kb)     : z2;
    float2 q5 = (kb + 3 < DD) ? *(const float2*)(hrow + kb + 2) : z2;
    float2 q6 = (kb + 5 < DD) ? *(const float2*)(hrow + kb + 4) : z2;
    float2 q7 = (kb + 7 < DD) ? *(const float2*)(hrow + kb + 6) : z2;

    bf16x8 a0, a1;
    a0[0] = f2b(q0.x); a0[1] = f2b(q0.y); a0[2] = f2b(q1.x); a0[3] = f2b(q1.y);
    a0[4] = f2b(q2.x); a0[5] = f2b(q2.y); a0[6] = f2b(q3.x); a0[7] = f2b(q3.y);
    a1[0] = f2b(q4.x); a1[1] = f2b(q4.y); a1[2] = f2b(q5.x); a1[3] = f2b(q5.y);
    a1[4] = f2b(q6.x); a1[5] = f2b(q6.y); a1[6] = f2b(q7.x); a1[7] = f2b(q7.y);

    // B frags: wb[r][n][k], lane n = lane&15 (+16t), k chunk = ch*8 (+32 for ks1)
    const unsigned short* wr = wb + ((size_t)r << 12) + ((lane & 15) << 6) + (ch << 3);
    f32x4 c[4];
    #pragma unroll
    for (int t = 0; t < 4; ++t) c[t] = (f32x4){0.f, 0.f, 0.f, 0.f};
    #pragma unroll
    for (int t = 0; t < 4; ++t) {
        bf16x8 b0 = *(const bf16x8*)(wr + t * 1024);
        bf16x8 b1 = *(const bf16x8*)(wr + t * 1024 + 32);
        c[t] = __builtin_amdgcn_mfma_f32_16x16x32_bf16(a0, b0, c[t], 0, 0, 0);
        c[t] = __builtin_amdgcn_mfma_f32_16x16x32_bf16(a1, b1, c[t], 0, 0, 0);
    }

    // C layout (m89): col = lane&15 (+16t), row = ch*4 + q. Coalesced row atomics.
    int col0 = lane & 15;
    #pragma unroll
    for (int q = 0; q < 4; ++q) {
        int rw = ch * 4 + q;
        int dq = __shfl(dv0, rw);                 // dst of row rw (-1 if invalid)
        if (dq >= 0) {
            float* op = out + (size_t)dq * DD;
            #pragma unroll
            for (int t = 0; t < 4; ++t) {
                int col = t * 16 + col0;
                if (col < DD) atomicAdd(op + col, c[t][q]);
            }
        }
    }
}

// out = relu(out + bias), float2 (row length 50 even -> pairs never cross rows)
__global__ void finalize_kernel(float* __restrict__ out, const float* __restrict__ bias, int total2) {
    int i = blockIdx.x * blockDim.x + threadIdx.x;
    if (i < total2) {
        float2 v = ((float2*)out)[i];
        int p = (i * 2) % DD;
        v.x += bias[p];
        v.y += bias[p + 1];
        v.x = v.x > 0.f ? v.x : 0.f;
        v.y = v.y > 0.f ? v.y : 0.f;
        ((float2*)out)[i] = v;
    }
}

extern "C" void kernel_launch(void* const* d_in, const int* in_sizes, int n_in,
                              void* d_out, int out_size, void* d_ws, size_t ws_size,
                              hipStream_t stream) {
    const float* h      = (const float*)d_in[0];
    const float* weight = (const float*)d_in[1];
    const float* bias   = (const float*)d_in[2];
    const int*   src    = (const int*)d_in[3];
    const int*   dst    = (const int*)d_in[4];
    const int*   rel    = (const int*)d_in[5];
    float* out = (float*)d_out;
    int*   meta = (int*)d_ws;
    unsigned short* wb = (unsigned short*)((char*)d_ws + WB_BYTE);

    const int E = in_sizes[3];

    init_kernel<<<2048, 256, 0, stream>>>((float4*)out, out_size / 4, meta, wb, weight);
    scatter_kernel<<<(E + 255) / 256, 256, 0, stream>>>(src, dst, rel, E, meta);
    compact_kernel<<<1, 1024, 0, stream>>>(meta);
    edge_kernel<<<WLMAX / 4, 256, 0, stream>>>(h, wb, meta, out);
    int total2 = out_size / 2;
    finalize_kernel<<<(total2 + 255) / 256, 256, 0, stream>>>(out, bias, total2);
}